// Round 2
// baseline (1097.894 us; speedup 1.0000x reference)
//
#include <hip/hip_runtime.h>

#define N_TOT 65536
#define K_CB  2048
#define D_DIM 256
#define HW    4096       // H*W
#define DHW   1048576    // D*H*W

// ws layout (4-byte element offsets):
//   cb2    [0, 2048)           float  (np-pairwise ||c_k||^2)
//   counts [2048, 4096)        int
//   sse    [4096]              float
//   idx    [4352, 69888)       int
//   z2     [69888, 135424)     float  (np-pairwise ||z_n||^2)

// numpy pairwise sum of squares, n=128 block (8-accumulator pattern), stride in elems.
__device__ __forceinline__ float pw128_sq(const float* __restrict__ base, int stride) {
    #pragma clang fp contract(off)
    float r[8];
    #pragma unroll
    for (int j = 0; j < 8; ++j) { float v = base[j * stride]; r[j] = v * v; }
    for (int i = 8; i < 128; i += 8) {
        #pragma unroll
        for (int j = 0; j < 8; ++j) { float v = base[(i + j) * stride]; r[j] += v * v; }
    }
    return ((r[0] + r[1]) + (r[2] + r[3])) + ((r[4] + r[5]) + (r[6] + r[7]));
}

// ||c_k||^2 in numpy pairwise order (n=256 -> 128+128). One thread per k.
__global__ void cb_norm_kernel(const float* __restrict__ cb, float* __restrict__ cb2) {
    #pragma clang fp contract(off)
    int k = blockIdx.x * 256 + threadIdx.x;
    const float* row = cb + (size_t)k * D_DIM;
    cb2[k] = pw128_sq(row, 1) + pw128_sq(row + 128, 1);
}

// ||z_n||^2 in numpy pairwise order. One thread per row n; d-stride is HW so
// adjacent threads (adjacent s) are coalesced per d.
__global__ void z_norm_kernel(const float* __restrict__ z, float* __restrict__ z2) {
    #pragma clang fp contract(off)
    int n = blockIdx.x * 256 + threadIdx.x;
    int b = n >> 12, s = n & 4095;
    const float* base = z + (size_t)b * DHW + s;
    z2[n] = pw128_sq(base, HW) + pw128_sq(base + (size_t)128 * HW, HW);
}

// Fused distance-GEMM + argmin. Tile: 128 rows x 128 codes, 256 threads,
// 8x8 micro-tile per thread. Score emulates np fp32 exactly:
//   score = fl( fl(z2 + c2_k) - fl(2*dot) )   (2*dot is an exact doubling)
__launch_bounds__(256, 4)
__global__ void argmin_kernel(const float* __restrict__ z, const float* __restrict__ cb,
                              const float* __restrict__ cb2, const float* __restrict__ z2arr,
                              int* __restrict__ idxout) {
    __shared__ __align__(16) float zt[32 * 128];   // zt[d][row]
    __shared__ __align__(16) float ct[32 * 132];   // ct[d][k], padded stride 132
    __shared__ unsigned long long rowmin[128];

    int t = threadIdx.x;
    int n0 = blockIdx.x * 128;
    const float* zbase = z + (size_t)(n0 >> 12) * DHW + (n0 & 4095);
    int tr = t & 15, tk = t >> 4;

    if (t < 128) rowmin[t] = 0xFFFFFFFFFFFFFFFFull;

    float zrow2[8];
    #pragma unroll
    for (int i = 0; i < 8; ++i)
        zrow2[i] = z2arr[n0 + tr * 4 + (i & 3) + (i >> 2) * 64];

    float acc[8][8];
    for (int kt = 0; kt < 16; ++kt) {
        int k0 = kt * 128;
        #pragma unroll
        for (int i = 0; i < 8; ++i)
            #pragma unroll
            for (int j = 0; j < 8; ++j) acc[i][j] = 0.f;

        for (int dc = 0; dc < 8; ++dc) {
            int d0 = dc * 32;
            __syncthreads();
            #pragma unroll
            for (int v = 0; v < 4; ++v) {
                int vi = t + v * 256;
                int d = vi >> 5;
                int rg = vi & 31;
                float4 val = *(const float4*)(zbase + (size_t)(d0 + d) * HW + rg * 4);
                *(float4*)&zt[d * 128 + rg * 4] = val;
            }
            #pragma unroll
            for (int v = 0; v < 4; ++v) {
                int vi = t + v * 256;
                int k = vi >> 3;
                int dg = vi & 7;
                float4 val = *(const float4*)(cb + (size_t)(k0 + k) * D_DIM + d0 + dg * 4);
                int d = dg * 4;
                ct[(d + 0) * 132 + k] = val.x;
                ct[(d + 1) * 132 + k] = val.y;
                ct[(d + 2) * 132 + k] = val.z;
                ct[(d + 3) * 132 + k] = val.w;
            }
            __syncthreads();
            #pragma unroll 4
            for (int d = 0; d < 32; ++d) {
                float4 za = *(const float4*)&zt[d * 128 + tr * 4];
                float4 zb = *(const float4*)&zt[d * 128 + tr * 4 + 64];
                float4 ca = *(const float4*)&ct[d * 132 + tk * 4];
                float4 cc = *(const float4*)&ct[d * 132 + tk * 4 + 64];
                float zr[8] = {za.x, za.y, za.z, za.w, zb.x, zb.y, zb.z, zb.w};
                float cr[8] = {ca.x, ca.y, ca.z, ca.w, cc.x, cc.y, cc.z, cc.w};
                #pragma unroll
                for (int i = 0; i < 8; ++i)
                    #pragma unroll
                    for (int j = 0; j < 8; ++j)
                        acc[i][j] += zr[i] * cr[j];
            }
        }
        float c2[8]; int kk[8];
        #pragma unroll
        for (int j = 0; j < 8; ++j) {
            kk[j] = k0 + tk * 4 + (j & 3) + (j >> 2) * 64;   // ascending in j
            c2[j] = cb2[kk[j]];
        }
        #pragma unroll
        for (int i = 0; i < 8; ++i) {
            float best = 0.f; int bk = 0;
            #pragma unroll
            for (int j = 0; j < 8; ++j) {
                float t1 = zrow2[i] + c2[j];            // fl(z2 + c2)
                float m2 = acc[i][j] + acc[i][j];       // exact fl(2*dot)
                float sc = t1 - m2;                     // fl(t1 - 2*dot)
                if (j == 0 || sc < best) { best = sc; bk = kk[j]; }  // tie -> lower k
            }
            unsigned u = __float_as_uint(best);
            u = (u & 0x80000000u) ? ~u : (u | 0x80000000u);  // orderable-uint map
            unsigned long long key = ((unsigned long long)u << 32) | (unsigned)bk;
            int row = tr * 4 + (i & 3) + (i >> 2) * 64;
            atomicMin(&rowmin[row], key);                    // tie -> lower k
        }
    }
    __syncthreads();
    if (t < 128) idxout[n0 + t] = (int)(rowmin[t] & 0xFFFFFFFFull);
}

// Gather q (transposed write), SSE for losses, histogram counts.
__global__ void gather_kernel(const float* __restrict__ z, const float* __restrict__ cb,
                              const int* __restrict__ idxin, float* __restrict__ qout,
                              float* __restrict__ sse, int* __restrict__ counts) {
    int t = threadIdx.x;
    int si = t & 63, dg = t >> 6;
    int n = blockIdx.x * 64 + si;
    int idx = idxin[n];
    int b = n >> 12, s = n & 4095;
    const float* zb = z + (size_t)b * DHW + s;
    float*       qb = qout + (size_t)b * DHW + s;
    const float4* crow = (const float4*)(cb + (size_t)idx * D_DIM + dg * 64);
    float acc = 0.f;
    #pragma unroll
    for (int dd4 = 0; dd4 < 16; ++dd4) {
        float4 q4 = crow[dd4];
        float qv[4] = {q4.x, q4.y, q4.z, q4.w};
        #pragma unroll
        for (int u = 0; u < 4; ++u) {
            int d = dg * 64 + dd4 * 4 + u;
            float zv = zb[(size_t)d * HW];
            qb[(size_t)d * HW] = qv[u];
            float df = zv - qv[u];
            acc += df * df;
        }
    }
    #pragma unroll
    for (int off = 32; off > 0; off >>= 1) acc += __shfl_down(acc, off, 64);
    if ((t & 63) == 0) atomicAdd(sse, acc);
    if (dg == 0) atomicAdd(&counts[idx], 1);
}

__global__ void finalize_kernel(const float* __restrict__ sse, const int* __restrict__ counts,
                                float* __restrict__ out) {
    int t = threadIdx.x;
    float mse = *sse * (1.0f / 16777216.0f);   // /(N*D)
    if (t == 0) {
        out[16777216] = mse * 1.25f;  // loss
        out[16777217] = mse;          // codebook_loss
        out[16777218] = mse;          // commitment_loss
    }
    for (int i = t; i < 2048; i += 256) out[16777219 + i] = (float)counts[i];
}

extern "C" void kernel_launch(void* const* d_in, const int* in_sizes, int n_in,
                              void* d_out, int out_size, void* d_ws, size_t ws_size,
                              hipStream_t stream) {
    const float* z  = (const float*)d_in[0];
    const float* cb = (const float*)d_in[1];
    float* out = (float*)d_out;
    float* ws  = (float*)d_ws;

    float* cb2    = ws;                 // [0,2048)
    int*   counts = (int*)(ws + 2048);  // [2048,4096)
    float* sse    = ws + 4096;          // [4096]
    int*   idx    = (int*)(ws + 4352);  // [4352,69888)
    float* z2     = ws + 69888;         // [69888,135424)

    hipMemsetAsync((char*)d_ws + 8192, 0, 9216, stream);  // counts + sse

    cb_norm_kernel<<<8, 256, 0, stream>>>(cb, cb2);
    z_norm_kernel<<<256, 256, 0, stream>>>(z, z2);
    argmin_kernel<<<512, 256, 0, stream>>>(z, cb, cb2, z2, idx);
    gather_kernel<<<1024, 256, 0, stream>>>(z, cb, idx, out, sse, counts);
    finalize_kernel<<<1, 256, 0, stream>>>(sse, counts, out);
}

// Round 3
// 533.610 us; speedup vs baseline: 2.0575x; 2.0575x over previous
//
#include <hip/hip_runtime.h>

#define N_TOT 65536
#define K_CB  2048
#define D_DIM 256
#define HW    4096       // H*W
#define DHW   1048576    // D*H*W

typedef _Float16 half8 __attribute__((ext_vector_type(8)));
typedef _Float16 half4v __attribute__((ext_vector_type(4)));
typedef float f32x4 __attribute__((ext_vector_type(4)));

// ws layout (4-byte element offsets):
//   cb2      [0, 2048)          float (np-pairwise ||c_k||^2)
//   counts   [2048, 4096)       int
//   sse      [4096]             float
//   z2       [4352, 69888)      float (np-pairwise ||z_n||^2)
//   rowmin_g [69888, 200960)    u64 x 65536 (byte 279552, 8-aligned)
//   c_hi     [200960, 463104)   fp16 x 524288  (codebook * 2^14, hi part)
//   c_lo     [463104, 725248)   fp16 x 524288  (lo part)
// z splits live in d_out[0..16777216) floats (overwritten later by q):
//   z_hi = (fp16*)d_out            [65536][256], z * 2^11 hi part
//   z_lo = z_hi + 16777216         lo part

__device__ __forceinline__ void gload_lds16(const void* g, void* l) {
    __builtin_amdgcn_global_load_lds((const __attribute__((address_space(1))) void*)g,
                                     (__attribute__((address_space(3))) void*)l, 16, 0, 0);
}

// ---------- numpy-exact norms (unchanged from R2, which passed exactly) ----------
__device__ __forceinline__ float pw128_sq(const float* __restrict__ base, int stride) {
    #pragma clang fp contract(off)
    float r[8];
    #pragma unroll
    for (int j = 0; j < 8; ++j) { float v = base[j * stride]; r[j] = v * v; }
    for (int i = 8; i < 128; i += 8) {
        #pragma unroll
        for (int j = 0; j < 8; ++j) { float v = base[(i + j) * stride]; r[j] += v * v; }
    }
    return ((r[0] + r[1]) + (r[2] + r[3])) + ((r[4] + r[5]) + (r[6] + r[7]));
}

__global__ void cb_norm_kernel(const float* __restrict__ cb, float* __restrict__ cb2) {
    #pragma clang fp contract(off)
    int k = blockIdx.x * 256 + threadIdx.x;
    const float* row = cb + (size_t)k * D_DIM;
    cb2[k] = pw128_sq(row, 1) + pw128_sq(row + 128, 1);
}

__global__ void z_norm_kernel(const float* __restrict__ z, float* __restrict__ z2) {
    #pragma clang fp contract(off)
    int n = blockIdx.x * 256 + threadIdx.x;
    int b = n >> 12, s = n & 4095;
    const float* base = z + (size_t)b * DHW + s;
    z2[n] = pw128_sq(base, HW) + pw128_sq(base + (size_t)128 * HW, HW);
}

// ---------- fp16 2-way splits ----------
// z' = z * 2^11, transpose (b,d,h,w) -> [n][d] row-major while splitting.
__global__ void split_z_kernel(const float* __restrict__ z,
                               _Float16* __restrict__ zh, _Float16* __restrict__ zl) {
    __shared__ float lt[64 * 65];
    int t = threadIdx.x;
    int nt = blockIdx.x >> 2, dt = blockIdx.x & 3;
    int n0 = nt * 64, d0 = dt * 64;
    int b = n0 >> 12, s0 = n0 & 4095;
    const float* zb = z + (size_t)b * DHW + s0;
    #pragma unroll
    for (int v = 0; v < 4; ++v) {
        int f = v * 256 + t;
        int d = f >> 4, nx = f & 15;
        float4 val = *(const float4*)(zb + (size_t)(d0 + d) * HW + nx * 4);
        lt[d * 65 + nx * 4 + 0] = val.x;
        lt[d * 65 + nx * 4 + 1] = val.y;
        lt[d * 65 + nx * 4 + 2] = val.z;
        lt[d * 65 + nx * 4 + 3] = val.w;
    }
    __syncthreads();
    #pragma unroll
    for (int v = 0; v < 4; ++v) {
        int g = v * 256 + t;
        int n = g >> 4, du = g & 15;
        half4v hh, hl;
        #pragma unroll
        for (int u = 0; u < 4; ++u) {
            float x = lt[(du * 4 + u) * 65 + n] * 2048.0f;   // 2^11, exact scale
            _Float16 h = (_Float16)x;                        // RTNE
            hh[u] = h;
            hl[u] = (_Float16)(x - (float)h);                // residual, exact sub
        }
        size_t off = (size_t)(n0 + n) * 256 + d0 + du * 4;
        *(half4v*)(zh + off) = hh;
        *(half4v*)(zl + off) = hl;
    }
}

// c' = c * 2^14 (keeps lo parts out of fp16-subnormal flush territory)
__global__ void split_c_kernel(const float* __restrict__ cb,
                               _Float16* __restrict__ ch, _Float16* __restrict__ cl) {
    int e = (blockIdx.x * 256 + threadIdx.x) * 4;   // 512 blocks -> 524288 elems
    float4 v = *(const float4*)(cb + e);
    float xs[4] = {v.x, v.y, v.z, v.w};
    half4v hh, hl;
    #pragma unroll
    for (int u = 0; u < 4; ++u) {
        float x = xs[u] * 16384.0f;                  // 2^14, exact scale
        _Float16 h = (_Float16)x;
        hh[u] = h;
        hl[u] = (_Float16)(x - (float)h);
    }
    *(half4v*)(ch + e) = hh;
    *(half4v*)(cl + e) = hl;
}

// ---------- MFMA distance + argmin ----------
// Block: 128 rows x 1024 codes. grid = 512 row-tiles x 2 code-halves = 1024.
// GEMM: A_cat=[zh|zh|zl], B_cat=[ch|cl|ch], K_eff=768 (12 x BK64), fp16 MFMA 16x16x32.
// acc = 2^25 * dot;  m2 = 2*dot = acc * 2^-24 (exact);  score = (z2+c2) - m2.
__launch_bounds__(256, 3)
__global__ void argmin_mfma_kernel(const _Float16* __restrict__ zh, const _Float16* __restrict__ zl,
                                   const _Float16* __restrict__ ch, const _Float16* __restrict__ cl,
                                   const float* __restrict__ cb2, const float* __restrict__ z2arr,
                                   unsigned long long* __restrict__ rowmin_g) {
    __shared__ __align__(16) _Float16 lds_a[8192];   // 128 rows x 64 k, XOR-swizzled 16B units
    __shared__ __align__(16) _Float16 lds_b[8192];
    __shared__ unsigned long long rowmin[128];

    int t = threadIdx.x;
    int r0  = (blockIdx.x >> 1) * 128;
    int cb0 = (blockIdx.x & 1) * 1024;
    int w = t >> 6, lane = t & 63;
    int wi = w & 1, wj = w >> 1;
    int lhi = lane >> 4, llo = lane & 15;

    if (t < 128) rowmin[t] = ~0ull;

    float z2r[16];
    #pragma unroll
    for (int x = 0; x < 16; ++x)
        z2r[x] = z2arr[r0 + wi * 64 + (x >> 2) * 16 + lhi * 4 + (x & 3)];
    __syncthreads();

    for (int ct = 0; ct < 8; ++ct) {
        int c0 = cb0 + ct * 128;
        f32x4 acc[4][4];
        #pragma unroll
        for (int i = 0; i < 4; ++i)
            #pragma unroll
            for (int j = 0; j < 4; ++j) acc[i][j] = (f32x4){0.f, 0.f, 0.f, 0.f};

        float c2v[4];
        #pragma unroll
        for (int j = 0; j < 4; ++j)
            c2v[j] = cb2[c0 + wj * 64 + j * 16 + llo];

        for (int ki = 0; ki < 12; ++ki) {
            int seg  = ki >> 2;
            int koff = (ki & 3) * 64;
            const _Float16* asrc = (seg < 2) ? zh : zl;
            const _Float16* bsrc = (seg == 1) ? cl : ch;
            __syncthreads();
            #pragma unroll
            for (int v = 0; v < 4; ++v) {
                int p = v * 256 + t;          // physical 16B unit
                int row = p >> 3;
                int kul = (p & 7) ^ (row & 7); // logical k-unit (inverse swizzle on source)
                gload_lds16(asrc + (size_t)(r0 + row) * 256 + koff + kul * 8, lds_a + p * 8);
                gload_lds16(bsrc + (size_t)(c0 + row) * 256 + koff + kul * 8, lds_b + p * 8);
            }
            __syncthreads();
            #pragma unroll
            for (int s = 0; s < 2; ++s) {
                half8 af[4], bf[4];
                #pragma unroll
                for (int i = 0; i < 4; ++i) {
                    int row = wi * 64 + i * 16 + llo;
                    int ku  = (s * 4 + lhi) ^ (row & 7);
                    af[i] = *(half8*)(lds_a + row * 64 + ku * 8);
                }
                #pragma unroll
                for (int j = 0; j < 4; ++j) {
                    int row = wj * 64 + j * 16 + llo;
                    int ku  = (s * 4 + lhi) ^ (row & 7);
                    bf[j] = *(half8*)(lds_b + row * 64 + ku * 8);
                }
                #pragma unroll
                for (int i = 0; i < 4; ++i)
                    #pragma unroll
                    for (int j = 0; j < 4; ++j)
                        acc[i][j] = __builtin_amdgcn_mfma_f32_16x16x32_f16(af[i], bf[j], acc[i][j], 0, 0, 0);
            }
        }

        // epilogue: score + argmin. D[m][n]: n = llo (+j*16+wj*64), m = lhi*4+r (+i*16+wi*64)
        #pragma unroll
        for (int i = 0; i < 4; ++i) {
            #pragma unroll
            for (int r = 0; r < 4; ++r) {
                float zz = z2r[i * 4 + r];
                unsigned long long key = ~0ull;
                #pragma unroll
                for (int j = 0; j < 4; ++j) {
                    float sc = (zz + c2v[j]) - acc[i][j][r] * (1.0f / 16777216.0f); // *2^-24 exact
                    unsigned long long k2 = ((unsigned long long)__float_as_uint(sc) << 32)
                                          | (unsigned)(c0 + wj * 64 + j * 16 + llo);
                    key = (k2 < key) ? k2 : key;          // tie -> lower code
                }
                // butterfly min over the 16 lanes sharing this m (llo varies)
                #pragma unroll
                for (int m = 1; m < 16; m <<= 1) {
                    unsigned lo = (unsigned)key, hi = (unsigned)(key >> 32);
                    unsigned olo = __shfl_xor(lo, m);
                    unsigned ohi = __shfl_xor(hi, m);
                    unsigned long long o = ((unsigned long long)ohi << 32) | olo;
                    key = (o < key) ? o : key;
                }
                if (llo == 0)
                    atomicMin(&rowmin[wi * 64 + i * 16 + lhi * 4 + r], key);
            }
        }
    }
    __syncthreads();
    if (t < 128) atomicMin(&rowmin_g[r0 + t], rowmin[t]);
}

// ---------- gather q, SSE, histogram ----------
__global__ void gather_kernel(const float* __restrict__ z, const float* __restrict__ cb,
                              const unsigned long long* __restrict__ rowmin_g,
                              float* __restrict__ qout,
                              float* __restrict__ sse, int* __restrict__ counts) {
    int t = threadIdx.x;
    int si = t & 63, dg = t >> 6;
    int n = blockIdx.x * 64 + si;
    int idx = (int)(rowmin_g[n] & 0xFFFFFFFFull);
    int b = n >> 12, s = n & 4095;
    const float* zb = z + (size_t)b * DHW + s;
    float*       qb = qout + (size_t)b * DHW + s;
    const float4* crow = (const float4*)(cb + (size_t)idx * D_DIM + dg * 64);
    float acc = 0.f;
    #pragma unroll
    for (int dd4 = 0; dd4 < 16; ++dd4) {
        float4 q4 = crow[dd4];
        float qv[4] = {q4.x, q4.y, q4.z, q4.w};
        #pragma unroll
        for (int u = 0; u < 4; ++u) {
            int d = dg * 64 + dd4 * 4 + u;
            float zv = zb[(size_t)d * HW];
            qb[(size_t)d * HW] = qv[u];
            float df = zv - qv[u];
            acc += df * df;
        }
    }
    #pragma unroll
    for (int off = 32; off > 0; off >>= 1) acc += __shfl_down(acc, off, 64);
    if ((t & 63) == 0) atomicAdd(sse, acc);
    if (dg == 0) atomicAdd(&counts[idx], 1);
}

__global__ void finalize_kernel(const float* __restrict__ sse, const int* __restrict__ counts,
                                float* __restrict__ out) {
    int t = threadIdx.x;
    float mse = *sse * (1.0f / 16777216.0f);   // /(N*D)
    if (t == 0) {
        out[16777216] = mse * 1.25f;  // loss
        out[16777217] = mse;          // codebook_loss
        out[16777218] = mse;          // commitment_loss
    }
    for (int i = t; i < 2048; i += 256) out[16777219 + i] = (float)counts[i];
}

extern "C" void kernel_launch(void* const* d_in, const int* in_sizes, int n_in,
                              void* d_out, int out_size, void* d_ws, size_t ws_size,
                              hipStream_t stream) {
    const float* z  = (const float*)d_in[0];
    const float* cb = (const float*)d_in[1];
    float* out = (float*)d_out;
    float* ws  = (float*)d_ws;

    float* cb2    = ws;                                    // [0,2048)
    int*   counts = (int*)(ws + 2048);                     // [2048,4096)
    float* sse    = ws + 4096;                             // [4096]
    float* z2     = ws + 4352;                             // [4352,69888)
    unsigned long long* rowmin_g = (unsigned long long*)(ws + 69888);  // 512 KB
    _Float16* ch  = (_Float16*)(ws + 200960);              // 1 MB
    _Float16* cl  = (_Float16*)(ws + 463104);              // 1 MB

    _Float16* zzh = (_Float16*)d_out;                      // 32 MB (overwritten by q later)
    _Float16* zzl = zzh + 16777216;                        // 32 MB

    hipMemsetAsync((char*)d_ws + 8192, 0, 8196, stream);          // counts + sse
    hipMemsetAsync((char*)d_ws + 279552, 0xFF, 524288, stream);   // rowmin_g = ~0

    split_z_kernel<<<4096, 256, 0, stream>>>(z, zzh, zzl);
    split_c_kernel<<<512, 256, 0, stream>>>(cb, ch, cl);
    cb_norm_kernel<<<8, 256, 0, stream>>>(cb, cb2);
    z_norm_kernel<<<256, 256, 0, stream>>>(z, z2);
    argmin_mfma_kernel<<<1024, 256, 0, stream>>>(zzh, zzl, ch, cl, cb2, z2, rowmin_g);
    gather_kernel<<<1024, 256, 0, stream>>>(z, cb, rowmin_g, out, sse, counts);
    finalize_kernel<<<1, 256, 0, stream>>>(sse, counts, out);
}

// Round 4
// 514.311 us; speedup vs baseline: 2.1347x; 1.0375x over previous
//
#include <hip/hip_runtime.h>

#define N_TOT 65536
#define K_CB  2048
#define D_DIM 256
#define HW    4096       // H*W
#define DHW   1048576    // D*H*W

typedef _Float16 half8 __attribute__((ext_vector_type(8)));
typedef _Float16 half4v __attribute__((ext_vector_type(4)));
typedef float f32x16 __attribute__((ext_vector_type(16)));

// ws layout (4-byte element offsets):
//   cb2      [0, 2048)          float (np-pairwise ||c_k||^2)
//   counts   [2048, 4096)       int
//   sse      [4096]             float
//   z2       [4352, 69888)      float (np-pairwise ||z_n||^2)
//   rowmin_g [69888, 200960)    u64 x 65536 (byte 279552)
//   c_hi     [200960, 463104)   fp16 x 524288  (codebook * 2^14, hi)
//   c_lo     [463104, 725248)   fp16 x 524288  (lo)
// z splits live in d_out[0..16777216) floats (overwritten later by q):
//   z_hi = (fp16*)d_out  [65536][256] row-major, z * 2^11 hi;  z_lo follows.

__device__ __forceinline__ void gload_lds16(const void* g, void* l) {
    __builtin_amdgcn_global_load_lds((const __attribute__((address_space(1))) void*)g,
                                     (__attribute__((address_space(3))) void*)l, 16, 0, 0);
}

// ---------- numpy-exact norms (verified exact in R2/R3) ----------
__device__ __forceinline__ float pw128_sq(const float* __restrict__ base, int stride) {
    #pragma clang fp contract(off)
    float r[8];
    #pragma unroll
    for (int j = 0; j < 8; ++j) { float v = base[j * stride]; r[j] = v * v; }
    for (int i = 8; i < 128; i += 8) {
        #pragma unroll
        for (int j = 0; j < 8; ++j) { float v = base[(i + j) * stride]; r[j] += v * v; }
    }
    return ((r[0] + r[1]) + (r[2] + r[3])) + ((r[4] + r[5]) + (r[6] + r[7]));
}

__global__ void cb_norm_kernel(const float* __restrict__ cb, float* __restrict__ cb2) {
    #pragma clang fp contract(off)
    int k = blockIdx.x * 256 + threadIdx.x;
    const float* row = cb + (size_t)k * D_DIM;
    cb2[k] = pw128_sq(row, 1) + pw128_sq(row + 128, 1);
}

// rows 128/block; thread groups t<128 / t>=128 compute the two independent
// 128-element np-pairwise halves, LDS-combined in np order (left + right).
__global__ void z_norm_kernel(const float* __restrict__ z, float* __restrict__ z2) {
    __shared__ float h[256];
    int t = threadIdx.x;
    int n = blockIdx.x * 128 + (t & 127);
    int hf = t >> 7;
    int b = n >> 12, s = n & 4095;
    const float* base = z + (size_t)b * DHW + s + (size_t)hf * 128 * HW;
    h[t] = pw128_sq(base, HW);
    __syncthreads();
    if (t < 128) z2[n] = h[t] + h[t + 128];
}

// ---------- fp16 2-way splits ----------
__global__ void split_z_kernel(const float* __restrict__ z,
                               _Float16* __restrict__ zh, _Float16* __restrict__ zl) {
    __shared__ float lt[64 * 65];
    int t = threadIdx.x;
    int nt = blockIdx.x >> 2, dt = blockIdx.x & 3;
    int n0 = nt * 64, d0 = dt * 64;
    int b = n0 >> 12, s0 = n0 & 4095;
    const float* zb = z + (size_t)b * DHW + s0;
    #pragma unroll
    for (int v = 0; v < 4; ++v) {
        int f = v * 256 + t;
        int d = f >> 4, nx = f & 15;
        float4 val = *(const float4*)(zb + (size_t)(d0 + d) * HW + nx * 4);
        lt[d * 65 + nx * 4 + 0] = val.x;
        lt[d * 65 + nx * 4 + 1] = val.y;
        lt[d * 65 + nx * 4 + 2] = val.z;
        lt[d * 65 + nx * 4 + 3] = val.w;
    }
    __syncthreads();
    #pragma unroll
    for (int v = 0; v < 4; ++v) {
        int g = v * 256 + t;
        int n = g >> 4, du = g & 15;
        half4v hh, hl;
        #pragma unroll
        for (int u = 0; u < 4; ++u) {
            float x = lt[(du * 4 + u) * 65 + n] * 2048.0f;   // 2^11 exact
            _Float16 hv = (_Float16)x;
            hh[u] = hv;
            hl[u] = (_Float16)(x - (float)hv);
        }
        size_t off = (size_t)(n0 + n) * 256 + d0 + du * 4;
        *(half4v*)(zh + off) = hh;
        *(half4v*)(zl + off) = hl;
    }
}

__global__ void split_c_kernel(const float* __restrict__ cb,
                               _Float16* __restrict__ ch, _Float16* __restrict__ cl) {
    int e = (blockIdx.x * 256 + threadIdx.x) * 4;
    float4 v = *(const float4*)(cb + e);
    float xs[4] = {v.x, v.y, v.z, v.w};
    half4v hh, hl;
    #pragma unroll
    for (int u = 0; u < 4; ++u) {
        float x = xs[u] * 16384.0f;                  // 2^14 exact
        _Float16 hv = (_Float16)x;
        hh[u] = hv;
        hl[u] = (_Float16)(x - (float)hv);
    }
    *(half4v*)(ch + e) = hh;
    *(half4v*)(cl + e) = hl;
}

// ---------- MFMA distance + argmin ----------
// Block: 128 rows x 256 codes, single accumulator pass over K_eff=768
// (A_cat=[zh|zh|zl], B_cat=[ch|cl|ch], 12 x BK64). MFMA 32x32x16_f16.
// Wave grid 2x2: wave-tile 64 rows x 128 codes, acc[2][4] f32x16.
// acc = 2^25*dot; m2 = acc*2^-24 exact; score = (z2+c2) - m2 (matches np fp32).
__launch_bounds__(256, 2)
__global__ void argmin_mfma_kernel(const _Float16* __restrict__ zh, const _Float16* __restrict__ zl,
                                   const _Float16* __restrict__ ch, const _Float16* __restrict__ cl,
                                   const float* __restrict__ cb2, const float* __restrict__ z2arr,
                                   unsigned long long* __restrict__ rowmin_g) {
    __shared__ __align__(16) _Float16 lds_a[8192];    // 128 rows x 64 k (16B-unit XOR swizzle)
    __shared__ __align__(16) _Float16 lds_b[16384];   // 256 codes x 64 k
    __shared__ unsigned long long rowmin[128];

    int t = threadIdx.x;
    int r0 = (blockIdx.x >> 3) * 128;
    int c0 = (blockIdx.x & 7) * 256;
    int w = t >> 6, lane = t & 63;
    int wi = w & 1, wj = w >> 1;
    int l31 = lane & 31, l5 = lane >> 5;

    if (t < 128) rowmin[t] = ~0ull;

    f32x16 acc[2][4];
    #pragma unroll
    for (int i = 0; i < 2; ++i)
        #pragma unroll
        for (int j = 0; j < 4; ++j)
            #pragma unroll
            for (int r = 0; r < 16; ++r) acc[i][j][r] = 0.f;

    float c2v[4];
    #pragma unroll
    for (int j = 0; j < 4; ++j)
        c2v[j] = cb2[c0 + wj * 128 + j * 32 + l31];

    for (int ki = 0; ki < 12; ++ki) {
        int seg  = ki >> 2;
        int koff = (ki & 3) * 64;
        const _Float16* asrc = (seg < 2) ? zh : zl;
        const _Float16* bsrc = (seg == 1) ? cl : ch;
        __syncthreads();
        #pragma unroll
        for (int v = 0; v < 4; ++v) {           // A: 1024 16B-units
            int p = v * 256 + t;
            int row = p >> 3;
            int ku = (p & 7) ^ (row & 7);       // inverse swizzle on global source
            gload_lds16(asrc + (size_t)(r0 + row) * 256 + koff + ku * 8, lds_a + p * 8);
        }
        #pragma unroll
        for (int v = 0; v < 8; ++v) {           // B: 2048 16B-units
            int p = v * 256 + t;
            int row = p >> 3;
            int ku = (p & 7) ^ (row & 7);
            gload_lds16(bsrc + (size_t)(c0 + row) * 256 + koff + ku * 8, lds_b + p * 8);
        }
        __syncthreads();
        #pragma unroll
        for (int ks = 0; ks < 4; ++ks) {        // 4 k-steps of 16
            half8 af[2], bf[4];
            #pragma unroll
            for (int i = 0; i < 2; ++i) {
                int row = wi * 64 + i * 32 + l31;
                int ku  = (ks * 2 + l5) ^ (row & 7);
                af[i] = *(half8*)(lds_a + row * 64 + ku * 8);
            }
            #pragma unroll
            for (int j = 0; j < 4; ++j) {
                int row = wj * 128 + j * 32 + l31;
                int ku  = (ks * 2 + l5) ^ (row & 7);
                bf[j] = *(half8*)(lds_b + row * 64 + ku * 8);
            }
            #pragma unroll
            for (int i = 0; i < 2; ++i)
                #pragma unroll
                for (int j = 0; j < 4; ++j)
                    acc[i][j] = __builtin_amdgcn_mfma_f32_32x32x16_f16(af[i], bf[j], acc[i][j], 0, 0, 0);
        }
    }

    // Epilogue (once per block). D mapping (32x32): col=lane&31,
    // row = (reg&3) + 8*(reg>>2) + 4*(lane>>5).
    #pragma unroll
    for (int i = 0; i < 2; ++i) {
        #pragma unroll
        for (int rg = 0; rg < 16; ++rg) {
            int rowoff = (rg & 3) + 8 * (rg >> 2) + 4 * l5;
            int m = wi * 64 + i * 32 + rowoff;
            float zz = z2arr[r0 + m];
            unsigned long long key = ~0ull;
            #pragma unroll
            for (int j = 0; j < 4; ++j) {
                float sc = (zz + c2v[j]) - acc[i][j][rg] * (1.0f / 16777216.0f);
                unsigned long long k2 = ((unsigned long long)__float_as_uint(sc) << 32)
                                      | (unsigned)(c0 + wj * 128 + j * 32 + l31);
                key = (k2 < key) ? k2 : key;         // scores >= 0: raw bits orderable
            }
            #pragma unroll
            for (int mm = 1; mm < 32; mm <<= 1) {    // min over the 32-lane group
                unsigned lo = (unsigned)key, hi = (unsigned)(key >> 32);
                unsigned olo = __shfl_xor(lo, mm);
                unsigned ohi = __shfl_xor(hi, mm);
                unsigned long long o = ((unsigned long long)ohi << 32) | olo;
                key = (o < key) ? o : key;
            }
            if (l31 == 0) atomicMin(&rowmin[m], key);
        }
    }
    __syncthreads();
    if (t < 128) atomicMin(&rowmin_g[r0 + t], rowmin[t]);
}

// ---------- gather q, SSE, histogram ----------
__global__ void gather_kernel(const float* __restrict__ z, const float* __restrict__ cb,
                              const unsigned long long* __restrict__ rowmin_g,
                              float* __restrict__ qout,
                              float* __restrict__ sse, int* __restrict__ counts) {
    int t = threadIdx.x;
    int si = t & 63, dg = t >> 6;
    int n = blockIdx.x * 64 + si;
    int idx = (int)(rowmin_g[n] & 0xFFFFFFFFull);
    int b = n >> 12, s = n & 4095;
    const float* zb = z + (size_t)b * DHW + s;
    float*       qb = qout + (size_t)b * DHW + s;
    const float4* crow = (const float4*)(cb + (size_t)idx * D_DIM + dg * 64);
    float acc = 0.f;
    #pragma unroll
    for (int dd4 = 0; dd4 < 16; ++dd4) {
        float4 q4 = crow[dd4];
        float qv[4] = {q4.x, q4.y, q4.z, q4.w};
        #pragma unroll
        for (int u = 0; u < 4; ++u) {
            int d = dg * 64 + dd4 * 4 + u;
            float zv = zb[(size_t)d * HW];
            qb[(size_t)d * HW] = qv[u];
            float df = zv - qv[u];
            acc += df * df;
        }
    }
    #pragma unroll
    for (int off = 32; off > 0; off >>= 1) acc += __shfl_down(acc, off, 64);
    if ((t & 63) == 0) atomicAdd(sse, acc);
    if (dg == 0) atomicAdd(&counts[idx], 1);
}

__global__ void finalize_kernel(const float* __restrict__ sse, const int* __restrict__ counts,
                                float* __restrict__ out) {
    int t = threadIdx.x;
    float mse = *sse * (1.0f / 16777216.0f);   // /(N*D)
    if (t == 0) {
        out[16777216] = mse * 1.25f;  // loss
        out[16777217] = mse;          // codebook_loss
        out[16777218] = mse;          // commitment_loss
    }
    for (int i = t; i < 2048; i += 256) out[16777219 + i] = (float)counts[i];
}

extern "C" void kernel_launch(void* const* d_in, const int* in_sizes, int n_in,
                              void* d_out, int out_size, void* d_ws, size_t ws_size,
                              hipStream_t stream) {
    const float* z  = (const float*)d_in[0];
    const float* cb = (const float*)d_in[1];
    float* out = (float*)d_out;
    float* ws  = (float*)d_ws;

    float* cb2    = ws;                                    // [0,2048)
    int*   counts = (int*)(ws + 2048);                     // [2048,4096)
    float* sse    = ws + 4096;                             // [4096]
    float* z2     = ws + 4352;                             // [4352,69888)
    unsigned long long* rowmin_g = (unsigned long long*)(ws + 69888);  // 512 KB
    _Float16* ch  = (_Float16*)(ws + 200960);              // 1 MB
    _Float16* cl  = (_Float16*)(ws + 463104);              // 1 MB

    _Float16* zzh = (_Float16*)d_out;                      // 32 MB (overwritten by q later)
    _Float16* zzl = zzh + 16777216;                        // 32 MB

    hipMemsetAsync((char*)d_ws + 8192, 0, 8196, stream);          // counts + sse
    hipMemsetAsync((char*)d_ws + 279552, 0xFF, 524288, stream);   // rowmin_g = ~0

    split_z_kernel<<<4096, 256, 0, stream>>>(z, zzh, zzl);
    split_c_kernel<<<512, 256, 0, stream>>>(cb, ch, cl);
    cb_norm_kernel<<<8, 256, 0, stream>>>(cb, cb2);
    z_norm_kernel<<<512, 256, 0, stream>>>(z, z2);
    argmin_mfma_kernel<<<4096, 256, 0, stream>>>(zzh, zzl, ch, cl, cb2, z2, rowmin_g);
    gather_kernel<<<1024, 256, 0, stream>>>(z, cb, rowmin_g, out, sse, counts);
    finalize_kernel<<<1, 256, 0, stream>>>(sse, counts, out);
}

// Round 6
// 461.821 us; speedup vs baseline: 2.3773x; 1.1137x over previous
//
#include <hip/hip_runtime.h>

#define N_TOT 65536
#define K_CB  2048
#define D_DIM 256
#define HW    4096       // H*W
#define DHW   1048576    // D*H*W

typedef _Float16 half8 __attribute__((ext_vector_type(8)));
typedef _Float16 half4v __attribute__((ext_vector_type(4)));
typedef float f32x16 __attribute__((ext_vector_type(16)));

// ws layout (4-byte element offsets):
//   cb2      [0, 2048)          float (np-pairwise ||c_k||^2)
//   counts   [2048, 4096)       int
//   sse      [4096]             float
//   z2       [4352, 69888)      float (np-pairwise ||z_n||^2)
//   rowmin_g [69888, 200960)    u64 x 65536
//   c_hi     [200960, 463104)   fp16 x 524288  (codebook * 2^14, hi)
//   c_lo     [463104, 725248)   fp16 x 524288  (lo)
// z splits live in d_out[0..16777216) floats (overwritten later by q):
//   z_hi = (fp16*)d_out  [65536][256] row-major, z * 2^11 hi;  z_lo follows.

__device__ __forceinline__ void gload_lds16(const void* g, void* l) {
    __builtin_amdgcn_global_load_lds((const __attribute__((address_space(1))) void*)g,
                                     (__attribute__((address_space(3))) void*)l, 16, 0, 0);
}

// ---------- codebook norms (np-pairwise, verified exact) + zero counts/sse ----------
__device__ __forceinline__ float pw128_sq(const float* __restrict__ base, int stride) {
    #pragma clang fp contract(off)
    float r[8];
    #pragma unroll
    for (int j = 0; j < 8; ++j) { float v = base[j * stride]; r[j] = v * v; }
    for (int i = 8; i < 128; i += 8) {
        #pragma unroll
        for (int j = 0; j < 8; ++j) { float v = base[(i + j) * stride]; r[j] += v * v; }
    }
    return ((r[0] + r[1]) + (r[2] + r[3])) + ((r[4] + r[5]) + (r[6] + r[7]));
}

__global__ void cbnorm_zero_kernel(const float* __restrict__ cb, float* __restrict__ cb2,
                                   int* __restrict__ counts, float* __restrict__ sse) {
    #pragma clang fp contract(off)
    int k = blockIdx.x * 256 + threadIdx.x;
    const float* row = cb + (size_t)k * D_DIM;
    cb2[k] = pw128_sq(row, 1) + pw128_sq(row + 128, 1);
    counts[k] = 0;
    if (k == 0) *sse = 0.f;
}

__global__ void split_c_kernel(const float* __restrict__ cb,
                               _Float16* __restrict__ ch, _Float16* __restrict__ cl) {
    int e = (blockIdx.x * 256 + threadIdx.x) * 4;
    float4 v = *(const float4*)(cb + e);
    float xs[4] = {v.x, v.y, v.z, v.w};
    half4v hh, hl;
    #pragma unroll
    for (int u = 0; u < 4; ++u) {
        float x = xs[u] * 16384.0f;                  // 2^14 exact
        _Float16 hv = (_Float16)x;
        hh[u] = hv;
        hl[u] = (_Float16)(x - (float)hv);           // exact sub, then RTNE
    }
    *(half4v*)(ch + e) = hh;
    *(half4v*)(cl + e) = hl;
}

// ---------- fused: z transpose+split, np-exact z2, rowmin_g init ----------
// Block: 32 rows x 256 d. 2048 blocks x 256 threads.
__global__ void fused_z_kernel(const float* __restrict__ z,
                               _Float16* __restrict__ zh, _Float16* __restrict__ zl,
                               float* __restrict__ z2,
                               unsigned long long* __restrict__ rowmin_g) {
    __shared__ __align__(16) float lt[256 * 33];   // lt[d][n], pad stride 33
    __shared__ float rj[512];                      // [n(32)][half(2)][j(8)]
    __shared__ float hh[64];                       // [half(2)][n(32)]
    int t = threadIdx.x;
    int n0 = blockIdx.x * 32;
    int b = n0 >> 12, s0 = n0 & 4095;
    const float* zb = z + (size_t)b * DHW + s0;

    #pragma unroll
    for (int v = 0; v < 8; ++v) {                  // 2048 float4 loads
        int f = v * 256 + t;
        int d = f >> 3, nch = f & 7;
        float4 val = *(const float4*)(zb + (size_t)d * HW + nch * 4);
        lt[d * 33 + nch * 4 + 0] = val.x;
        lt[d * 33 + nch * 4 + 1] = val.y;
        lt[d * 33 + nch * 4 + 2] = val.z;
        lt[d * 33 + nch * 4 + 3] = val.w;
    }
    __syncthreads();

    // np-pairwise partials: thread (n, j) accumulates r_j over i*8+j, both halves.
    {
        #pragma clang fp contract(off)
        int n = t & 31, j = t >> 5;                // j in 0..7
        #pragma unroll
        for (int hf = 0; hf < 2; ++hf) {
            float r = 0.f;
            #pragma unroll
            for (int i = 0; i < 16; ++i) {
                float v = lt[(hf * 128 + i * 8 + j) * 33 + n];
                r += v * v;
            }
            rj[n * 16 + hf * 8 + j] = r;
        }
    }

    // split writes: zh/zl row-major [n][d]
    #pragma unroll
    for (int v = 0; v < 8; ++v) {
        int g = v * 256 + t;
        int n = g >> 6, du = g & 63;
        half4v hv, lv;
        #pragma unroll
        for (int u = 0; u < 4; ++u) {
            float x = lt[(du * 4 + u) * 33 + n] * 2048.0f;   // 2^11 exact
            _Float16 h = (_Float16)x;
            hv[u] = h;
            lv[u] = (_Float16)(x - (float)h);
        }
        size_t off = (size_t)(n0 + n) * 256 + du * 4;
        *(half4v*)(zh + off) = hv;
        *(half4v*)(zl + off) = lv;
    }
    __syncthreads();

    if (t < 64) {                                  // np combine per (n, half)
        #pragma clang fp contract(off)
        int n = t & 31, hf = t >> 5;
        const float* r = &rj[n * 16 + hf * 8];
        hh[hf * 32 + n] = ((r[0] + r[1]) + (r[2] + r[3])) + ((r[4] + r[5]) + (r[6] + r[7]));
    }
    __syncthreads();
    if (t < 32) {
        #pragma clang fp contract(off)
        z2[n0 + t] = hh[t] + hh[32 + t];           // half0 + half1, np order
        rowmin_g[n0 + t] = ~0ull;
    }
}

// ---------- MFMA distance + argmin ----------
// Block: 128 rows x 256 codes, single acc pass over K_eff=768
// (A_cat=[zh|zh|zl], B_cat=[ch|cl|ch], 12 x BK64). MFMA 32x32x16_f16.
// acc = 2^25*dot; m2 = acc*2^-24 exact; score = (z2+c2) - m2 (matches np fp32).
__launch_bounds__(256, 2)
__global__ void argmin_mfma_kernel(const _Float16* __restrict__ zh, const _Float16* __restrict__ zl,
                                   const _Float16* __restrict__ ch, const _Float16* __restrict__ cl,
                                   const float* __restrict__ cb2, const float* __restrict__ z2arr,
                                   unsigned long long* __restrict__ rowmin_g) {
    __shared__ __align__(16) char lds_raw[49152];
    _Float16* lds_a = (_Float16*)lds_raw;            // 128 rows x 64 k (16B-unit XOR swizzle)
    _Float16* lds_b = (_Float16*)(lds_raw + 16384);  // 256 codes x 64 k

    int t = threadIdx.x;
    int r0 = (blockIdx.x >> 3) * 128;
    int c0 = (blockIdx.x & 7) * 256;
    int w = t >> 6, lane = t & 63;
    int wi = w & 1, wj = w >> 1;
    int l31 = lane & 31, l5 = lane >> 5;

    f32x16 acc[2][4];
    #pragma unroll
    for (int i = 0; i < 2; ++i)
        #pragma unroll
        for (int j = 0; j < 4; ++j)
            #pragma unroll
            for (int r = 0; r < 16; ++r) acc[i][j][r] = 0.f;

    float c2v[4];
    #pragma unroll
    for (int j = 0; j < 4; ++j)
        c2v[j] = cb2[c0 + wj * 128 + j * 32 + l31];

    for (int ki = 0; ki < 12; ++ki) {
        int seg  = ki >> 2;
        int koff = (ki & 3) * 64;
        const _Float16* asrc = (seg < 2) ? zh : zl;
        const _Float16* bsrc = (seg == 1) ? cl : ch;
        __syncthreads();
        #pragma unroll
        for (int v = 0; v < 4; ++v) {           // A: 1024 16B-units
            int p = v * 256 + t;
            int row = p >> 3;
            int ku = (p & 7) ^ (row & 7);       // inverse swizzle on global source
            gload_lds16(asrc + (size_t)(r0 + row) * 256 + koff + ku * 8, lds_a + p * 8);
        }
        #pragma unroll
        for (int v = 0; v < 8; ++v) {           // B: 2048 16B-units
            int p = v * 256 + t;
            int row = p >> 3;
            int ku = (p & 7) ^ (row & 7);
            gload_lds16(bsrc + (size_t)(c0 + row) * 256 + koff + ku * 8, lds_b + p * 8);
        }
        __syncthreads();
        #pragma unroll
        for (int ks = 0; ks < 4; ++ks) {        // 4 k-steps of 16
            half8 af[2], bf[4];
            #pragma unroll
            for (int i = 0; i < 2; ++i) {
                int row = wi * 64 + i * 32 + l31;
                int ku  = (ks * 2 + l5) ^ (row & 7);
                af[i] = *(half8*)(lds_a + row * 64 + ku * 8);
            }
            #pragma unroll
            for (int j = 0; j < 4; ++j) {
                int row = wj * 128 + j * 32 + l31;
                int ku  = (ks * 2 + l5) ^ (row & 7);
                bf[j] = *(half8*)(lds_b + row * 64 + ku * 8);
            }
            #pragma unroll
            for (int i = 0; i < 2; ++i)
                #pragma unroll
                for (int j = 0; j < 4; ++j)
                    acc[i][j] = __builtin_amdgcn_mfma_f32_32x32x16_f16(af[i], bf[j], acc[i][j], 0, 0, 0);
        }
    }

    // Epilogue. D mapping (32x32): col=lane&31, row=(reg&3)+8*(reg>>2)+4*(lane>>5).
    // Phase 1: lane j-min -> xor16 pair-min -> 16 keys/row/wave into LDS scratch.
    __syncthreads();                              // protect lds_a/lds_b reuse
    unsigned long long* scratch = (unsigned long long*)lds_raw;   // 128 x 34 u64
    #pragma unroll
    for (int i = 0; i < 2; ++i) {
        #pragma unroll
        for (int rg = 0; rg < 16; ++rg) {
            int rowoff = (rg & 3) + 8 * (rg >> 2) + 4 * l5;
            int m = wi * 64 + i * 32 + rowoff;
            float zz = z2arr[r0 + m];
            unsigned long long key = ~0ull;
            #pragma unroll
            for (int j = 0; j < 4; ++j) {
                float sc = (zz + c2v[j]) - acc[i][j][rg] * (1.0f / 16777216.0f);
                unsigned long long k2 = ((unsigned long long)__float_as_uint(sc) << 32)
                                      | (unsigned)(c0 + wj * 128 + j * 32 + l31);
                key = (k2 < key) ? k2 : key;      // scores > 0: raw bits orderable
            }
            {   // pair-min with lane^16 (stays within the 32-lane m-group)
                unsigned lo = (unsigned)key, hi = (unsigned)(key >> 32);
                unsigned olo = __shfl_xor(lo, 16);
                unsigned ohi = __shfl_xor(hi, 16);
                unsigned long long o = ((unsigned long long)ohi << 32) | olo;
                key = (o < key) ? o : key;
            }
            if (l31 < 16) scratch[m * 34 + wj * 16 + l31] = key;
        }
    }
    __syncthreads();
    // Phase 2: one thread per row reduces its 32 keys, one global atomic per row.
    if (t < 128) {
        const ulonglong2* srow = (const ulonglong2*)(scratch + t * 34);
        unsigned long long best = ~0ull;
        #pragma unroll
        for (int s = 0; s < 16; ++s) {
            ulonglong2 p = srow[s];
            if (p.x < best) best = p.x;
            if (p.y < best) best = p.y;
        }
        atomicMin(&rowmin_g[r0 + t], best);
    }
}

// ---------- gather q, SSE, histogram ----------
__global__ void gather_kernel(const float* __restrict__ z, const float* __restrict__ cb,
                              const unsigned long long* __restrict__ rowmin_g,
                              float* __restrict__ qout,
                              float* __restrict__ sse, int* __restrict__ counts) {
    int t = threadIdx.x;
    int si = t & 63, dg = t >> 6;
    int n = blockIdx.x * 64 + si;
    int idx = (int)(rowmin_g[n] & 0xFFFFFFFFull);
    int b = n >> 12, s = n & 4095;
    const float* zb = z + (size_t)b * DHW + s;
    float*       qb = qout + (size_t)b * DHW + s;
    const float4* crow = (const float4*)(cb + (size_t)idx * D_DIM + dg * 64);
    float acc = 0.f;
    #pragma unroll
    for (int dd4 = 0; dd4 < 16; ++dd4) {
        float4 q4 = crow[dd4];
        float qv[4] = {q4.x, q4.y, q4.z, q4.w};
        #pragma unroll
        for (int u = 0; u < 4; ++u) {
            int d = dg * 64 + dd4 * 4 + u;
            float zv = zb[(size_t)d * HW];
            qb[(size_t)d * HW] = qv[u];
            float df = zv - qv[u];
            acc += df * df;
        }
    }
    #pragma unroll
    for (int off = 32; off > 0; off >>= 1) acc += __shfl_down(acc, off, 64);
    if ((t & 63) == 0) atomicAdd(sse, acc);
    if (dg == 0) atomicAdd(&counts[idx], 1);
}

__global__ void finalize_kernel(const float* __restrict__ sse, const int* __restrict__ counts,
                                float* __restrict__ out) {
    int t = threadIdx.x;
    float mse = *sse * (1.0f / 16777216.0f);   // /(N*D)
    if (t == 0) {
        out[16777216] = mse * 1.25f;  // loss
        out[16777217] = mse;          // codebook_loss
        out[16777218] = mse;          // commitment_loss
    }
    for (int i = t; i < 2048; i += 256) out[16777219 + i] = (float)counts[i];
}

extern "C" void kernel_launch(void* const* d_in, const int* in_sizes, int n_in,
                              void* d_out, int out_size, void* d_ws, size_t ws_size,
                              hipStream_t stream) {
    const float* z  = (const float*)d_in[0];
    const float* cb = (const float*)d_in[1];
    float* out = (float*)d_out;
    float* ws  = (float*)d_ws;

    float* cb2    = ws;                                    // [0,2048)
    int*   counts = (int*)(ws + 2048);                     // [2048,4096)
    float* sse    = ws + 4096;                             // [4096]
    float* z2     = ws + 4352;                             // [4352,69888)
    unsigned long long* rowmin_g = (unsigned long long*)(ws + 69888);  // 512 KB
    _Float16* ch  = (_Float16*)(ws + 200960);              // 1 MB
    _Float16* cl  = (_Float16*)(ws + 463104);              // 1 MB

    _Float16* zzh = (_Float16*)d_out;                      // 32 MB (overwritten by q later)
    _Float16* zzl = zzh + 16777216;                        // 32 MB

    cbnorm_zero_kernel<<<8, 256, 0, stream>>>(cb, cb2, counts, sse);
    split_c_kernel<<<512, 256, 0, stream>>>(cb, ch, cl);
    fused_z_kernel<<<2048, 256, 0, stream>>>(z, zzh, zzl, z2, rowmin_g);
    argmin_mfma_kernel<<<4096, 256, 0, stream>>>(zzh, zzl, ch, cl, cb2, z2, rowmin_g);
    gather_kernel<<<1024, 256, 0, stream>>>(z, cb, rowmin_g, out, sse, counts);
    finalize_kernel<<<1, 256, 0, stream>>>(sse, counts, out);
}